// Round 2
// baseline (555.424 us; speedup 1.0000x reference)
//
#include <hip/hip_runtime.h>
#include <hip/hip_bf16.h>
#include <math.h>

#define B_SZ 128
#define I_DIM 512
#define H_DIM 1024
#define O_DIM 32
#define G4 4096          // 4*H
#define NSTEP 5          // only h2[4] is needed -> 5 timesteps
#define SPLITK 4

#define BM 64
#define BN 64
#define BK 16

// C_part[z] = A[:, zKC:(z+1)KC] @ B[:, zKC:(z+1)KC]^T  (+ same chunk of pair 2)
// A: [M, lda] row-major, B: [N, ldb] row-major (both K-contiguous -> NT gemm)
__global__ __launch_bounds__(256) void gemm_nt(
    const float* __restrict__ A, int lda,
    const float* __restrict__ B, int ldb,
    const float* __restrict__ A2,   // optional second pair (shares lda/ldb)
    const float* __restrict__ B2,
    float* __restrict__ C, int ldc, long long partStride, int KC)
{
    __shared__ float As[BK][BM + 4];
    __shared__ float Bs[BK][BN + 4];
    const int tid = threadIdx.x;
    const int tx = tid & 15;        // 0..15 -> n
    const int ty = tid >> 4;        // 0..15 -> m
    const int lr = tid >> 2;        // 0..63  staging row
    const int lk = (tid & 3) * 4;   // 0,4,8,12 staging k
    const int bn = blockIdx.x * BN;
    const int bm = blockIdx.y * BM;
    const int z  = blockIdx.z;
    const int k0base = z * KC;

    float acc[4][4] = {};

    for (int pair = 0; pair < 2; ++pair) {
        const float* Ap = pair ? A2 : A;
        const float* Bp = pair ? B2 : B;
        if (!Ap) break;   // uniform
        const float* aptr = Ap + (long long)(bm + lr) * lda + k0base + lk;
        const float* bptr = Bp + (long long)(bn + lr) * ldb + k0base + lk;
        for (int k0 = 0; k0 < KC; k0 += BK) {
            float4 av = *(const float4*)(aptr + k0);
            float4 bv = *(const float4*)(bptr + k0);
            __syncthreads();
            As[lk + 0][lr] = av.x; As[lk + 1][lr] = av.y;
            As[lk + 2][lr] = av.z; As[lk + 3][lr] = av.w;
            Bs[lk + 0][lr] = bv.x; Bs[lk + 1][lr] = bv.y;
            Bs[lk + 2][lr] = bv.z; Bs[lk + 3][lr] = bv.w;
            __syncthreads();
            #pragma unroll
            for (int kk = 0; kk < BK; ++kk) {
                const float4 a = *(const float4*)&As[kk][ty * 4];
                const float4 b = *(const float4*)&Bs[kk][tx * 4];
                acc[0][0] += a.x * b.x; acc[0][1] += a.x * b.y;
                acc[0][2] += a.x * b.z; acc[0][3] += a.x * b.w;
                acc[1][0] += a.y * b.x; acc[1][1] += a.y * b.y;
                acc[1][2] += a.y * b.z; acc[1][3] += a.y * b.w;
                acc[2][0] += a.z * b.x; acc[2][1] += a.z * b.y;
                acc[2][2] += a.z * b.z; acc[2][3] += a.z * b.w;
                acc[3][0] += a.w * b.x; acc[3][1] += a.w * b.y;
                acc[3][2] += a.w * b.z; acc[3][3] += a.w * b.w;
            }
        }
    }

    float* Cp = C + (long long)z * partStride;
    #pragma unroll
    for (int i = 0; i < 4; ++i) {
        float4 v = make_float4(acc[i][0], acc[i][1], acc[i][2], acc[i][3]);
        *(float4*)(Cp + (long long)(bm + ty * 4 + i) * ldc + bn + tx * 4) = v;
    }
}

// LSTM pointwise: sum split-K partials (+xg for layer0) + biases, update h,c
__global__ __launch_bounds__(256) void gates_kernel(
    const float* __restrict__ p0, const float* __restrict__ p1,
    const float* __restrict__ p2, const float* __restrict__ p3,
    const float* __restrict__ xg,   // may be null (layer 1)
    const float* __restrict__ b_ih, const float* __restrict__ b_hh,
    float* __restrict__ h, float* __restrict__ c)
{
    int idx = blockIdx.x * blockDim.x + threadIdx.x;
    if (idx >= B_SZ * H_DIM) return;
    int b = idx >> 10;             // H_DIM = 1024
    int j = idx & (H_DIM - 1);
    long long base = ((long long)b << 12) + j;   // b*4096 + j
    float g[4];
    #pragma unroll
    for (int q = 0; q < 4; ++q) {
        long long o = base + q * H_DIM;
        int jq = j + q * H_DIM;
        float v = p0[o] + p1[o] + p2[o] + p3[o] + b_ih[jq] + b_hh[jq];
        if (xg) v += xg[o];
        g[q] = v;
    }
    float ig = 1.f / (1.f + expf(-g[0]));
    float fg = 1.f / (1.f + expf(-g[1]));
    float gg = tanhf(g[2]);
    float og = 1.f / (1.f + expf(-g[3]));
    float cn = fg * c[idx] + ig * gg;
    c[idx] = cn;
    h[idx] = og * tanhf(cn);
}

__global__ void zero_kernel(float* __restrict__ p, int n)
{
    int i = blockIdx.x * blockDim.x + threadIdx.x;
    if (i < n) p[i] = 0.f;
}

// out[b][o] = h1[b,:] . w_out[o,:] + b_out[o]
__global__ __launch_bounds__(64) void head_kernel(
    const float* __restrict__ h, const float* __restrict__ w_out,
    const float* __restrict__ b_out, float* __restrict__ out)
{
    int o = blockIdx.x, b = blockIdx.y, lane = threadIdx.x;
    const float* hp = h + b * H_DIM;
    const float* wp = w_out + o * H_DIM;
    float s = 0.f;
    #pragma unroll
    for (int k = lane; k < H_DIM; k += 64) s += hp[k] * wp[k];
    #pragma unroll
    for (int off = 32; off; off >>= 1) s += __shfl_down(s, off);
    if (lane == 0) out[b * O_DIM + o] = s + b_out[o];
}

extern "C" void kernel_launch(void* const* d_in, const int* in_sizes, int n_in,
                              void* d_out, int out_size, void* d_ws, size_t ws_size,
                              hipStream_t stream)
{
    const float* input   = (const float*)d_in[0];
    const float* w_ih_l0 = (const float*)d_in[1];
    const float* w_hh_l0 = (const float*)d_in[2];
    const float* b_ih_l0 = (const float*)d_in[3];
    const float* b_hh_l0 = (const float*)d_in[4];
    const float* w_ih_l1 = (const float*)d_in[5];
    const float* w_hh_l1 = (const float*)d_in[6];
    const float* b_ih_l1 = (const float*)d_in[7];
    const float* b_hh_l1 = (const float*)d_in[8];
    const float* w_out   = (const float*)d_in[9];
    const float* b_out   = (const float*)d_in[10];
    float* out = (float*)d_out;

    const long long GATE = (long long)B_SZ * G4;   // 524288 floats
    float* ws    = (float*)d_ws;
    float* xg0   = ws;                       // NSTEP*GATE
    float* part0 = xg0 + NSTEP * GATE;       // SPLITK*GATE
    float* part1 = part0 + SPLITK * GATE;    // SPLITK*GATE
    float* h0    = part1 + SPLITK * GATE;    // B*H each, contiguous h0,c0,h1,c1
    float* c0    = h0 + B_SZ * H_DIM;
    float* h1    = c0 + B_SZ * H_DIM;
    float* c1    = h1 + B_SZ * H_DIM;

    // h/c start at zero (ws is poisoned 0xAA before every timed call)
    zero_kernel<<<(4 * B_SZ * H_DIM + 255) / 256, 256, 0, stream>>>(h0, 4 * B_SZ * H_DIM);

    // xg0[t*B+b, :] = input[t,b,:] @ w_ih_l0^T   for t=0..4  (M=640, K=512)
    gemm_nt<<<dim3(G4 / BN, (NSTEP * B_SZ) / BM, 1), 256, 0, stream>>>(
        input, I_DIM, w_ih_l0, I_DIM, nullptr, nullptr, xg0, G4, 0, I_DIM);

    for (int t = 0; t < NSTEP; ++t) {
        // layer 0 recurrent: part0[z] = h0 @ w_hh_l0^T (K split in 4)
        gemm_nt<<<dim3(G4 / BN, B_SZ / BM, SPLITK), 256, 0, stream>>>(
            h0, H_DIM, w_hh_l0, H_DIM, nullptr, nullptr, part0, G4, GATE, H_DIM / SPLITK);
        gates_kernel<<<(B_SZ * H_DIM) / 256, 256, 0, stream>>>(
            part0, part0 + GATE, part0 + 2 * GATE, part0 + 3 * GATE,
            xg0 + (long long)t * GATE, b_ih_l0, b_hh_l0, h0, c0);
        // layer 1 fused: part1[z] = h0 @ w_ih_l1^T + h1 @ w_hh_l1^T
        gemm_nt<<<dim3(G4 / BN, B_SZ / BM, SPLITK), 256, 0, stream>>>(
            h0, H_DIM, w_ih_l1, H_DIM, h1, w_hh_l1, part1, G4, GATE, H_DIM / SPLITK);
        gates_kernel<<<(B_SZ * H_DIM) / 256, 256, 0, stream>>>(
            part1, part1 + GATE, part1 + 2 * GATE, part1 + 3 * GATE,
            nullptr, b_ih_l1, b_hh_l1, h1, c1);
    }

    head_kernel<<<dim3(O_DIM, B_SZ), 64, 0, stream>>>(h1, w_out, b_out, out);
}